// Round 5
// baseline (426.925 us; speedup 1.0000x reference)
//
#include <hip/hip_runtime.h>

// cluster_layer: q[n,k] = (1/(1+||x_n - c_k||^2)) normalized over k  (alpha=1)
// N=1e6, D=64, K=20.
//
// History:
//  R2: 1 row/thread, divergent 16x dwordx4/row (64 lines/instr!), c via SGPR.
//      153 us, 1546 GB/s (19%).
//  R3: sched_barrier pin: +6 us (RA re-sank loads).
//  R4: persistent+NT: REGRESSION (WRITE 79->195 MB).
//  R5: v_pk_fma: +0 -> VALU-issue not binding.
//  R6: asm 16-deep vmcnt MLP: ~20 us (128 us). Latency covered, but each
//      x-load still touches 64 distinct cache lines -> TA/L1 request-
//      throughput wall. Deeper MLP can't fix address divergence.
//  R7: kill the divergence. Stage 256 rows (64 KB) per block via
//      global_load_lds width=16: linear LDS dest (HW: firstlane base +
//      lane*16), PRE-SWIZZLED per-lane global source (rule 21) -> every
//      instruction fetches 1 KB contiguous (8 lines). Zero VGPR defs ->
//      nothing to sink, full MLP, drained by __syncthreads. Compute reads
//      own row via ds_read_b128 at (tid*256+st*16)^(m*16): XOR swizzle
//      spreads the stride-256 column over all 32 banks (conflict-free).
//      csq -> tiny pre-kernel into d_ws (frees LDS to exactly 64 KB,
//      2 blocks/CU). c stays on the R2-proven SGPR stream.

#define NPTS 1000000
#define DIM  64
#define KCL  20
#define BLOCK 256
#define ROWS  256          // rows per block == BLOCK

typedef float f32x4 __attribute__((ext_vector_type(4)));

__global__ void csq_kernel(const float* __restrict__ c, float* __restrict__ csq)
{
    const int k = threadIdx.x;
    if (k < KCL) {
        const f32x4* c4 = (const f32x4*)c + k * (DIM / 4);
        float s = 0.f;
        #pragma unroll
        for (int m = 0; m < DIM / 4; ++m) {
            const f32x4 v = c4[m];
            s += v.x * v.x + v.y * v.y + v.z * v.z + v.w * v.w;
        }
        csq[k] = s;
    }
}

__global__ __launch_bounds__(BLOCK, 4) void cluster_q_kernel(
    const float* __restrict__ x,
    const float* __restrict__ c,
    const float* __restrict__ csq,
    float* __restrict__ out)
{
    // 64 KB: 256 rows x 16 chunks of 16 B, chunk index XOR-swizzled by (row&7)
    __shared__ f32x4 sX[ROWS][DIM / 4];

    const int tid  = threadIdx.x;
    const int wave = tid >> 6;
    const int lane = tid & 63;
    const size_t row0 = (size_t)blockIdx.x * ROWS;

    // ---- stage: 16 global_load_lds per wave, 1 KB contiguous each ----
    // LDS linear position (r, p): r = Q>>4, p = Q&15, Q = (wave*16+i)*64+lane.
    // Content must be x[row0+r][p ^ (r&7)]  (so the swizzled read recovers x).
    #pragma unroll
    for (int i = 0; i < 16; ++i) {
        const int ldsOff = (wave * 16 + i) * 1024;        // wave-uniform base
        const int r      = (wave * 16 + i) * 4 + (lane >> 4);
        size_t grow = row0 + r;
        if (grow > (size_t)(NPTS - 1)) grow = NPTS - 1;   // tail clamp (dup ok)
        const int srcChunk = (lane & 15) ^ (r & 7);       // pre-swizzled source
        const float* gsrc = x + grow * DIM + srcChunk * 4;
        __builtin_amdgcn_global_load_lds(
            (const __attribute__((address_space(1))) void*)gsrc,
            (__attribute__((address_space(3))) void*)((char*)&sX[0][0] + ldsOff),
            16, 0, 0);
    }
    __syncthreads();

    const size_t row = row0 + tid;
    if (row >= NPTS) return;

    // ---- compute: row from LDS (swizzled, conflict-free), c via SGPRs ----
    const int   st    = tid & 7;
    const int   base  = tid * 256 + st * 16;     // byte offset; ^ (m*16) walks chunks
    const char* sbase = (const char*)&sX[0][0];

    float acc[KCL];
    #pragma unroll
    for (int k = 0; k < KCL; ++k) acc[k] = 0.f;
    float xsq = 0.f;

    #pragma unroll
    for (int m = 0; m < DIM / 4; ++m) {
        const f32x4 xv = *(const f32x4*)(sbase + (base ^ (m * 16)));
        xsq += xv.x * xv.x + xv.y * xv.y + xv.z * xv.z + xv.w * xv.w;
        #pragma unroll
        for (int k = 0; k < KCL; ++k) {
            acc[k] += xv.x * c[k * DIM + 4 * m + 0]
                    + xv.y * c[k * DIM + 4 * m + 1]
                    + xv.z * c[k * DIM + 4 * m + 2]
                    + xv.w * c[k * DIM + 4 * m + 3];
        }
    }

    // epilogue: d2 -> q -> normalize -> 5 aligned float4 stores
    float s = 0.f;
    #pragma unroll
    for (int k = 0; k < KCL; ++k) {
        const float d2 = xsq + csq[k] - 2.0f * acc[k];    // csq: s_load, uniform
        const float qq = __builtin_amdgcn_rcpf(1.0f + d2);
        acc[k] = qq;
        s += qq;
    }
    const float inv = __builtin_amdgcn_rcpf(s);

    f32x4* o4 = (f32x4*)(out + row * KCL);
    #pragma unroll
    for (int k = 0; k < KCL; k += 4) {
        f32x4 v;
        v.x = acc[k + 0] * inv;
        v.y = acc[k + 1] * inv;
        v.z = acc[k + 2] * inv;
        v.w = acc[k + 3] * inv;
        o4[k / 4] = v;
    }
}

extern "C" void kernel_launch(void* const* d_in, const int* in_sizes, int n_in,
                              void* d_out, int out_size, void* d_ws, size_t ws_size,
                              hipStream_t stream) {
    const float* x = (const float*)d_in[0];   // (N, D) fp32
    const float* c = (const float*)d_in[1];   // (K, D) fp32
    float* out = (float*)d_out;               // (N, K) fp32
    float* csq = (float*)d_ws;                // 20 floats of workspace

    csq_kernel<<<1, 64, 0, stream>>>(c, csq);

    const int blocks = (NPTS + ROWS - 1) / ROWS;   // 3907
    cluster_q_kernel<<<blocks, BLOCK, 0, stream>>>(x, c, csq, out);
}